// Round 3
// baseline (6280.515 us; speedup 1.0000x reference)
//
#include <hip/hip_runtime.h>
#include <hip/hip_bf16.h>
#include <stdint.h>

typedef __hip_bfloat16 bf16;
typedef __attribute__((ext_vector_type(4))) float f32x4;
typedef __attribute__((ext_vector_type(8))) short short8v;
typedef __attribute__((ext_vector_type(4))) short short4v;

union U8 { short8v v; bf16 h[8]; };
union U4 { short4v v; bf16 h[4]; };

#define DEV static __device__ __forceinline__

DEV bf16 f2bf(float f) { return __float2bfloat16(f); }
DEV float bf2f(bf16 h) { return __bfloat162float(h); }

// ---------------------------------------------------------------- GEMM
// C(M,N) = act( A(M,K)bf16 @ BT(N,K)bf16^T + bias + Cin ), 128x128 tile, 4 waves
// Reg-staged LDS (no global_load_lds this round -- known-good semantics).
template<bool RELU, bool BIAS, bool ADDC, bool OBF16>
__global__ __launch_bounds__(256)
void gemm_bt(const bf16* __restrict__ A, const bf16* __restrict__ BT,
             const float* __restrict__ bias, const float* __restrict__ Cin,
             void* __restrict__ Dout, int M, int N, int K)
{
  __shared__ __align__(16) bf16 As[128*32];
  __shared__ __align__(16) bf16 Bs[128*32];
  const int tid = threadIdx.x;
  const int m0 = blockIdx.y * 128, n0 = blockIdx.x * 128;
  const int wid = tid >> 6, lane = tid & 63;
  const int wr = wid >> 1, wc = wid & 1;
  const int r = lane & 15, g = lane >> 4;

  const int srow = tid >> 2;
  const int scol = (tid & 3) * 8;
  const bf16* a0 = A + (size_t)(m0 + srow) * K + scol;
  const bf16* a1 = A + (size_t)(m0 + srow + 64) * K + scol;
  const bf16* b0 = BT + (size_t)(n0 + srow) * K + scol;
  const bf16* b1 = BT + (size_t)(n0 + srow + 64) * K + scol;
  bf16* asd  = &As[(size_t)tid * 8];
  bf16* asd2 = &As[2048 + (size_t)tid * 8];
  bf16* bsd  = &Bs[(size_t)tid * 8];
  bf16* bsd2 = &Bs[2048 + (size_t)tid * 8];

  f32x4 acc[4][4];
  #pragma unroll
  for (int i = 0; i < 4; ++i)
    #pragma unroll
    for (int j = 0; j < 4; ++j) acc[i][j] = (f32x4){0.f, 0.f, 0.f, 0.f};

  for (int kt = 0; kt < K; kt += 32) {
    const short8v ra  = *(const short8v*)(a0 + kt);
    const short8v ra2 = *(const short8v*)(a1 + kt);
    const short8v rb  = *(const short8v*)(b0 + kt);
    const short8v rb2 = *(const short8v*)(b1 + kt);
    __syncthreads();                       // prev iter's LDS reads done
    *(short8v*)asd  = ra;
    *(short8v*)asd2 = ra2;
    *(short8v*)bsd  = rb;
    *(short8v*)bsd2 = rb2;
    __syncthreads();                       // tile visible to all waves
    short8v af[4], bf_[4];
    #pragma unroll
    for (int mi = 0; mi < 4; ++mi)
      af[mi] = *(const short8v*)&As[(wr*64 + mi*16 + r)*32 + g*8];
    #pragma unroll
    for (int ni = 0; ni < 4; ++ni)
      bf_[ni] = *(const short8v*)&Bs[(wc*64 + ni*16 + r)*32 + g*8];
    #pragma unroll
    for (int mi = 0; mi < 4; ++mi)
      #pragma unroll
      for (int ni = 0; ni < 4; ++ni)
        acc[mi][ni] = __builtin_amdgcn_mfma_f32_16x16x32_bf16(af[mi], bf_[ni], acc[mi][ni], 0, 0, 0);
  }

  const int mbase = m0 + wr*64;
  const int nbase = n0 + wc*64;
  #pragma unroll
  for (int ni = 0; ni < 4; ++ni) {
    const int col = nbase + ni*16 + r;
    const float bv = BIAS ? bias[col] : 0.f;
    #pragma unroll
    for (int mi = 0; mi < 4; ++mi) {
      #pragma unroll
      for (int b4 = 0; b4 < 4; ++b4) {
        const int row = mbase + mi*16 + g*4 + b4;
        float v = acc[mi][ni][b4] + bv;
        if (ADDC) v += Cin[(size_t)row * N + col];
        if (RELU) v = fmaxf(v, 0.f);
        if (OBF16) ((bf16*)Dout)[(size_t)row * N + col] = f2bf(v);
        else       ((float*)Dout)[(size_t)row * N + col] = v;
      }
    }
  }
}

// ---------------------------------------------------------------- weights: W(K,N) f32 -> WT(N,K) bf16 (batched over z)
__global__ __launch_bounds__(256)
void transpose_w(const float* __restrict__ W, bf16* __restrict__ WT, int K, int N,
                 size_t sW, size_t sWT)
{
  const float* Wp = W + (size_t)blockIdx.z * sW;
  bf16* WTp = WT + (size_t)blockIdx.z * sWT;
  __shared__ float tl[32][33];
  const int n0 = blockIdx.x * 32, k0 = blockIdx.y * 32;
  const int r = threadIdx.x >> 5, c = threadIdx.x & 31;
  #pragma unroll
  for (int rr = r; rr < 32; rr += 8) tl[rr][c] = Wp[(size_t)(k0 + rr) * N + n0 + c];
  __syncthreads();
  #pragma unroll
  for (int rr = r; rr < 32; rr += 8) WTp[(size_t)(n0 + rr) * K + k0 + c] = f2bf(tl[c][rr]);
}

// ---------------------------------------------------------------- gather (chunked): X rows [row0, row0+grid)
__global__ __launch_bounds__(256)
void gather_kernel(const int* __restrict__ off_ids, const int* __restrict__ def_ids,
                   const int* __restrict__ off_pos, const int* __restrict__ def_pos,
                   const float* __restrict__ pemb, const float* __restrict__ remb,
                   int row0, bf16* __restrict__ X, int* __restrict__ cbuf)
{
  const int grow = row0 + blockIdx.x;
  const int b = grow / 10, t = grow % 10;
  int pid, pos, role;
  if (t < 5) { pid = off_ids[b*5 + t];   pos = off_pos[b*5 + t];   role = 0; }
  else       { pid = def_ids[b*5 + t-5]; pos = def_pos[b*5 + t-5]; role = 1; }
  const int col = threadIdx.x * 4;       // 0..1020
  const float* src = (col < 512) ? (pemb + (size_t)pid * 512 + col)
                                 : (remb + (size_t)role * 512 + (col - 512));
  f32x4 v = *(const f32x4*)src;
  U4 u;
  u.h[0] = f2bf(v[0]); u.h[1] = f2bf(v[1]); u.h[2] = f2bf(v[2]); u.h[3] = f2bf(v[3]);
  *(short4v*)(X + (size_t)blockIdx.x * 1024 + col) = u.v;
  if (threadIdx.x == 0) cbuf[grow] = role * 5 + pos;
}

// ---------------------------------------------------------------- LayerNorm rows of 512, f32 in -> bf16 out
__global__ __launch_bounds__(256)
void ln_kernel(const float* __restrict__ Zin, const float* __restrict__ gam,
               const float* __restrict__ bet, bf16* __restrict__ outp)
{
  const int w = threadIdx.x >> 6, lane = threadIdx.x & 63;
  const size_t row = (size_t)blockIdx.x * 4 + w;
  const float* zp = Zin + row * 512 + lane * 8;
  f32x4 v0 = *(const f32x4*)zp;
  f32x4 v1 = *(const f32x4*)(zp + 4);
  float s = 0.f, ss = 0.f;
  #pragma unroll
  for (int j = 0; j < 4; ++j) { s += v0[j]; ss += v0[j]*v0[j]; }
  #pragma unroll
  for (int j = 0; j < 4; ++j) { s += v1[j]; ss += v1[j]*v1[j]; }
  for (int d0 = 1; d0 < 64; d0 <<= 1) { s += __shfl_xor(s, d0); ss += __shfl_xor(ss, d0); }
  const float mu = s * (1.f/512.f);
  const float rstd = rsqrtf(ss * (1.f/512.f) - mu*mu + 1e-5f);
  const float* gp = gam + lane * 8;
  const float* bp = bet + lane * 8;
  f32x4 g0 = *(const f32x4*)gp, g1 = *(const f32x4*)(gp + 4);
  f32x4 b0 = *(const f32x4*)bp, b1 = *(const f32x4*)(bp + 4);
  U8 u;
  #pragma unroll
  for (int j = 0; j < 4; ++j) u.h[j]     = f2bf((v0[j]-mu)*rstd*g0[j] + b0[j]);
  #pragma unroll
  for (int j = 0; j < 4; ++j) u.h[4 + j] = f2bf((v1[j]-mu)*rstd*g1[j] + b1[j]);
  *(short8v*)(outp + row * 512 + lane * 8) = u.v;
}

// ---------------------------------------------------------------- attention: one wave per (local b, h)
__global__ __launch_bounds__(256)
void attn_kernel(const bf16* __restrict__ qkv, const int* __restrict__ cbuf,
                 const float* __restrict__ biasL, bf16* __restrict__ O)
{
  __shared__ __align__(16) bf16 Plds[4][256];    // 16x16 per wave
  __shared__ __align__(16) bf16 Vt[4][1024];     // 64x16 per wave (v^T, cols j>=10 zero)
  const int w = threadIdx.x >> 6, lane = threadIdx.x & 63;
  const int wv = blockIdx.x * 4 + w;
  const int b = wv >> 3, h = wv & 7;
  const int r = lane & 15, g = lane >> 4;
  const bf16* base = qkv + (size_t)b * 15360;    // 10*1536
  const bool rv = r < 10;
  const short8v z8 = {0,0,0,0,0,0,0,0};

  short8v aq0 = z8, aq1 = z8, bk0 = z8, bk1 = z8;
  if (rv) {
    const bf16* qp = base + (size_t)r * 1536 + h * 64 + g * 8;
    aq0 = *(const short8v*)qp;
    aq1 = *(const short8v*)(qp + 32);
    bk0 = *(const short8v*)(qp + 512);
    bk1 = *(const short8v*)(qp + 544);
  }
  f32x4 s = {0.f, 0.f, 0.f, 0.f};
  s = __builtin_amdgcn_mfma_f32_16x16x32_bf16(aq0, bk0, s, 0, 0, 0);
  s = __builtin_amdgcn_mfma_f32_16x16x32_bf16(aq1, bk1, s, 0, 0, 0);

  // stage V^T (j cols 10..15 zeroed)
  bf16* V = Vt[w];
  {
    const int j1 = lane >> 3, d0 = (lane & 7) * 8;
    U8 uv; uv.v = *(const short8v*)(base + (size_t)j1 * 1536 + 1024 + h * 64 + d0);
    #pragma unroll
    for (int m2 = 0; m2 < 8; ++m2) V[(d0 + m2) * 16 + j1] = uv.h[m2];
    const int j2 = 8 + j1;
    U8 uv2; uv2.v = z8;
    if (j2 < 10) uv2.v = *(const short8v*)(base + (size_t)j2 * 1536 + 1024 + h * 64 + d0);
    #pragma unroll
    for (int m2 = 0; m2 < 8; ++m2) V[(d0 + m2) * 16 + j2] = uv2.h[m2];
  }

  const int cj = rv ? cbuf[b * 10 + r] : 0;
  float sv[4];
  #pragma unroll
  for (int q4 = 0; q4 < 4; ++q4) {
    const int i = g * 4 + q4;
    float val = s[q4] * 0.125f;                       // 1/sqrt(64)
    if (rv && i < 10) val += biasL[h * 100 + cbuf[b * 10 + i] * 10 + cj];
    if (!rv) val = -1e30f;
    sv[q4] = val;
  }
  float mx[4];
  #pragma unroll
  for (int q4 = 0; q4 < 4; ++q4) mx[q4] = sv[q4];
  for (int d0 = 1; d0 < 16; d0 <<= 1) {
    #pragma unroll
    for (int q4 = 0; q4 < 4; ++q4) mx[q4] = fmaxf(mx[q4], __shfl_xor(mx[q4], d0));
  }
  float pe[4], sm[4];
  #pragma unroll
  for (int q4 = 0; q4 < 4; ++q4) { pe[q4] = __expf(sv[q4] - mx[q4]); sm[q4] = pe[q4]; }
  for (int d0 = 1; d0 < 16; d0 <<= 1) {
    #pragma unroll
    for (int q4 = 0; q4 < 4; ++q4) sm[q4] += __shfl_xor(sm[q4], d0);
  }

  bf16* P = Plds[w];
  #pragma unroll
  for (int q4 = 0; q4 < 4; ++q4) P[(g * 4 + q4) * 16 + r] = f2bf(pe[q4] / sm[q4]);

  short8v pa = z8;
  if (g < 2) pa = *(const short8v*)&P[r * 16 + g * 8];
  #pragma unroll
  for (int db = 0; db < 4; ++db) {
    short8v bv = z8;
    if (g < 2) bv = *(const short8v*)&V[(db * 16 + r) * 16 + g * 8];
    f32x4 o = {0.f, 0.f, 0.f, 0.f};
    o = __builtin_amdgcn_mfma_f32_16x16x32_bf16(pa, bv, o, 0, 0, 0);
    #pragma unroll
    for (int q4 = 0; q4 < 4; ++q4) {
      const int i = g * 4 + q4;
      if (i < 10) O[(size_t)(b * 10 + i) * 512 + h * 64 + db * 16 + r] = f2bf(o[q4]);
    }
  }
}

// ---------------------------------------------------------------- token mean: (8192,10,512) f32 -> (8192,512) bf16
__global__ __launch_bounds__(256)
void mean_kernel(const float* __restrict__ Zin, bf16* __restrict__ zm)
{
  const int idx = blockIdx.x * 256 + threadIdx.x;   // 8192*128
  const int b = idx >> 7, d4 = (idx & 127) << 2;
  const float* p = Zin + (size_t)b * 5120 + d4;
  f32x4 a = {0.f, 0.f, 0.f, 0.f};
  #pragma unroll
  for (int i = 0; i < 10; ++i) a += *(const f32x4*)(p + (size_t)i * 512);
  a *= 0.1f;
  U4 u;
  #pragma unroll
  for (int j = 0; j < 4; ++j) u.h[j] = f2bf(a[j]);
  *(short4v*)(zm + (size_t)b * 512 + d4) = u.v;
}

// ---------------------------------------------------------------- head2: (8192,512)bf16 @ (512,5)f32 + b2
__global__ __launch_bounds__(256)
void head2_kernel(const bf16* __restrict__ hh, const float* __restrict__ W2,
                  const float* __restrict__ b2, float* __restrict__ out)
{
  const int w = threadIdx.x >> 6, lane = threadIdx.x & 63;
  const int b = blockIdx.x * 4 + w;
  U8 u; u.v = *(const short8v*)(hh + (size_t)b * 512 + lane * 8);
  float p[5] = {0.f, 0.f, 0.f, 0.f, 0.f};
  #pragma unroll
  for (int j = 0; j < 8; ++j) {
    const float hf = bf2f(u.h[j]);
    const float* wp = W2 + (size_t)(lane * 8 + j) * 5;
    #pragma unroll
    for (int c = 0; c < 5; ++c) p[c] += hf * wp[c];
  }
  for (int d0 = 1; d0 < 64; d0 <<= 1) {
    #pragma unroll
    for (int c = 0; c < 5; ++c) p[c] += __shfl_xor(p[c], d0);
  }
  if (lane == 0) {
    float* op = out + (size_t)b * 5;
    #pragma unroll
    for (int c = 0; c < 5; ++c) op[c] = p[c] + b2[c];
  }
}

// ----------------------------------------------------------------
extern "C" void kernel_launch(void* const* d_in, const int* in_sizes, int n_in,
                              void* d_out, int out_size, void* d_ws, size_t ws_size,
                              hipStream_t stream)
{
  const int*   off_ids = (const int*)d_in[0];
  const int*   def_ids = (const int*)d_in[1];
  const int*   off_pos = (const int*)d_in[2];
  const int*   def_pos = (const int*)d_in[3];
  const float* pemb    = (const float*)d_in[4];
  const float* remb    = (const float*)d_in[5];
  const float* proj_W1 = (const float*)d_in[6];
  const float* proj_b1 = (const float*)d_in[7];
  const float* proj_W2 = (const float*)d_in[8];
  const float* proj_b2 = (const float*)d_in[9];
  const float* ln1_g   = (const float*)d_in[10];
  const float* ln1_b   = (const float*)d_in[11];
  const float* Wq      = (const float*)d_in[12];
  const float* Wk      = (const float*)d_in[13];
  const float* Wv      = (const float*)d_in[14];
  const float* Wo      = (const float*)d_in[15];
  const float* bias_B  = (const float*)d_in[16];
  const float* ln2_g   = (const float*)d_in[17];
  const float* ln2_b   = (const float*)d_in[18];
  const float* ffn_W1  = (const float*)d_in[19];
  const float* ffn_b1  = (const float*)d_in[20];
  const float* ffn_W2  = (const float*)d_in[21];
  const float* ffn_b2  = (const float*)d_in[22];
  const float* head_W1 = (const float*)d_in[23];
  const float* head_b1 = (const float*)d_in[24];
  const float* head_W2 = (const float*)d_in[25];
  const float* head_b2 = (const float*)d_in[26];
  (void)in_sizes; (void)n_in; (void)out_size;

  char* ws = (char*)d_ws;
  size_t off = 0;
  auto take = [&](size_t bytes) -> char* {
    char* p = ws + off; off += (bytes + 255) & ~(size_t)255; return p;
  };

  // ---- fixed allocations first
  float* Z     = (float*)take(81920ull * 512 * 4);       // residual, f32 (160MiB)
  bf16*  Wp1T  = (bf16*)take(1024ull * 1024 * 2);
  bf16*  Wp2T  = (bf16*)take(512ull * 1024 * 2);
  bf16*  Wh1T  = (bf16*)take(512ull * 512 * 2);
  bf16*  WqkvT = (bf16*)take(4ull * 1536 * 512 * 2);
  bf16*  WoT   = (bf16*)take(4ull * 512 * 512 * 2);
  bf16*  Wf1T  = (bf16*)take(4ull * 2048 * 512 * 2);
  bf16*  Wf2T  = (bf16*)take(4ull * 512 * 2048 * 2);
  int*   cbuf  = (int*)take(81920ull * 4);
  bf16*  zmean = (bf16*)take(8192ull * 512 * 2);
  bf16*  hh    = (bf16*)take(8192ull * 512 * 2);

  // ---- adaptive M-chunk: arena = Mc * 5KB must fit in remaining ws
  const size_t fixed_end = off;
  int Mc = 81920;
  while (Mc > 2560 && fixed_end + (size_t)Mc * 5120 + (1u << 20) > ws_size) Mc >>= 1;
  const int NCH = 81920 / Mc;
  char* arena = ws + fixed_end;

  // ---- weight transpose+convert (f32 (K,N) -> bf16 (N,K)), batched over layers
  auto T = [&](const float* W, bf16* WT, int K, int N, size_t sW, size_t sWT, int nz) {
    transpose_w<<<dim3(N / 32, K / 32, nz), 256, 0, stream>>>(W, WT, K, N, sW, sWT);
  };
  T(proj_W1, Wp1T, 1024, 1024, 0, 0, 1);
  T(proj_W2, Wp2T, 1024, 512, 0, 0, 1);
  T(head_W1, Wh1T, 512, 512, 0, 0, 1);
  T(Wq, WqkvT,          512, 512, 262144, 786432, 4);
  T(Wk, WqkvT + 262144, 512, 512, 262144, 786432, 4);
  T(Wv, WqkvT + 524288, 512, 512, 262144, 786432, 4);
  T(Wo, WoT,            512, 512, 262144, 262144, 4);
  T(ffn_W1, Wf1T, 512, 2048, 1048576, 1048576, 4);
  T(ffn_W2, Wf2T, 2048, 512, 1048576, 1048576, 4);

  // ---- embed gather + proj MLP (chunked)
  for (int c = 0; c < NCH; ++c) {
    const int r0 = c * Mc;
    bf16* Xc  = (bf16*)arena;                          // Mc x 1024 bf16
    bf16* H1c = (bf16*)(arena + (size_t)Mc * 2048);    // Mc x 1024 bf16
    gather_kernel<<<Mc, 256, 0, stream>>>(off_ids, def_ids, off_pos, def_pos,
                                          pemb, remb, r0, Xc, cbuf);
    gemm_bt<true,  true,  false, true ><<<dim3(8, Mc/128),  256, 0, stream>>>(Xc,  Wp1T, proj_b1, nullptr, H1c, Mc, 1024, 1024);
    gemm_bt<false, true,  false, false><<<dim3(4, Mc/128),  256, 0, stream>>>(H1c, Wp2T, proj_b2, nullptr, Z + (size_t)r0 * 512, Mc, 512, 1024);
  }

  // ---- transformer layers (chunked)
  for (int l = 0; l < 4; ++l) {
    for (int c = 0; c < NCH; ++c) {                    // attention sub-block
      const int r0 = c * Mc;
      float* Zc = Z + (size_t)r0 * 512;
      bf16* Z1c  = (bf16*)arena;                       // Mc x 512
      bf16* QKVc = (bf16*)(arena + (size_t)Mc * 1024); // Mc x 1536
      bf16* Oc   = (bf16*)(arena + (size_t)Mc * 4096); // Mc x 512
      ln_kernel<<<Mc/4, 256, 0, stream>>>(Zc, ln1_g + l*512, ln1_b + l*512, Z1c);
      gemm_bt<false, false, false, true ><<<dim3(12, Mc/128), 256, 0, stream>>>(Z1c, WqkvT + (size_t)l * 786432, nullptr, nullptr, QKVc, Mc, 1536, 512);
      attn_kernel<<<Mc/5, 256, 0, stream>>>(QKVc, cbuf + r0, bias_B + (size_t)l * 800, Oc);
      gemm_bt<false, false, true,  false><<<dim3(4, Mc/128),  256, 0, stream>>>(Oc, WoT + (size_t)l * 262144, nullptr, Zc, Zc, Mc, 512, 512);
    }
    for (int c = 0; c < NCH; ++c) {                    // FFN sub-block
      const int r0 = c * Mc;
      float* Zc = Z + (size_t)r0 * 512;
      bf16* Z2c = (bf16*)arena;                        // Mc x 512
      bf16* Hc  = (bf16*)(arena + (size_t)Mc * 1024);  // Mc x 2048
      ln_kernel<<<Mc/4, 256, 0, stream>>>(Zc, ln2_g + l*512, ln2_b + l*512, Z2c);
      gemm_bt<true,  true,  false, true ><<<dim3(16, Mc/128), 256, 0, stream>>>(Z2c, Wf1T + (size_t)l * 1048576, ffn_b1 + (size_t)l * 2048, nullptr, Hc, Mc, 2048, 512);
      gemm_bt<false, true,  true,  false><<<dim3(4, Mc/128),  256, 0, stream>>>(Hc, Wf2T + (size_t)l * 1048576, ffn_b2 + (size_t)l * 512, Zc, Zc, Mc, 512, 2048);
    }
  }

  // ---- head
  mean_kernel<<<4096, 256, 0, stream>>>(Z, zmean);
  gemm_bt<true, true, false, true><<<dim3(4, 64), 256, 0, stream>>>(zmean, Wh1T, head_b1, nullptr, hh, 8192, 512, 512);
  head2_kernel<<<2048, 256, 0, stream>>>(hh, head_W2, head_b2, (float*)d_out);
}

// Round 4
// 6224.968 us; speedup vs baseline: 1.0089x; 1.0089x over previous
//
#include <hip/hip_runtime.h>
#include <hip/hip_bf16.h>
#include <stdint.h>

typedef __hip_bfloat16 bf16;
typedef __attribute__((ext_vector_type(4))) float f32x4;
typedef __attribute__((ext_vector_type(8))) short short8v;
typedef __attribute__((ext_vector_type(4))) short short4v;

union U8 { short8v v; bf16 h[8]; };
union U4 { short4v v; bf16 h[4]; };

#define DEV static __device__ __forceinline__

DEV bf16 f2bf(float f) { return __float2bfloat16(f); }
DEV float bf2f(bf16 h) { return __bfloat162float(h); }

// Direct addrspacecast (NOT integer truncation -- that was the r0 fault suspect).
DEV void async_copy16(bf16* lds, const bf16* g) {
  __builtin_amdgcn_global_load_lds(
      (const __attribute__((address_space(1))) unsigned int*)g,
      (__attribute__((address_space(3))) unsigned int*)lds,
      16, 0, 0);
}

// ---------------------------------------------------------------- GEMM
// C(M,N) = act( A(M,K)bf16 @ BT(N,K)bf16^T + bias + Cin ), 128x128 tile, 4 waves
// global_load_lds width-16 staging (m97 structure).
template<bool RELU, bool BIAS, bool ADDC, bool OBF16>
__global__ __launch_bounds__(256)
void gemm_bt(const bf16* __restrict__ A, const bf16* __restrict__ BT,
             const float* __restrict__ bias, const float* __restrict__ Cin,
             void* __restrict__ Dout, int M, int N, int K)
{
  __shared__ __align__(16) bf16 As[128*32];
  __shared__ __align__(16) bf16 Bs[128*32];
  const int tid = threadIdx.x;
  const int m0 = blockIdx.y * 128, n0 = blockIdx.x * 128;
  const int wid = tid >> 6, lane = tid & 63;
  const int wr = wid >> 1, wc = wid & 1;
  const int r = lane & 15, g = lane >> 4;

  const int srow = tid >> 2;
  const int scol = (tid & 3) * 8;
  const bf16* a0 = A + (size_t)(m0 + srow) * K + scol;
  const bf16* a1 = A + (size_t)(m0 + srow + 64) * K + scol;
  const bf16* b0 = BT + (size_t)(n0 + srow) * K + scol;
  const bf16* b1 = BT + (size_t)(n0 + srow + 64) * K + scol;
  bf16* asd  = &As[(size_t)tid * 8];          // tid*16B: wave-uniform base + lane*16 (linear)
  bf16* asd2 = &As[2048 + (size_t)tid * 8];
  bf16* bsd  = &Bs[(size_t)tid * 8];
  bf16* bsd2 = &Bs[2048 + (size_t)tid * 8];

  f32x4 acc[4][4];
  #pragma unroll
  for (int i = 0; i < 4; ++i)
    #pragma unroll
    for (int j = 0; j < 4; ++j) acc[i][j] = (f32x4){0.f, 0.f, 0.f, 0.f};

  for (int kt = 0; kt < K; kt += 32) {
    async_copy16(asd,  a0 + kt);
    async_copy16(asd2, a1 + kt);
    async_copy16(bsd,  b0 + kt);
    async_copy16(bsd2, b1 + kt);
    __syncthreads();                       // compiler drains vmcnt before barrier
    short8v af[4], bf_[4];
    #pragma unroll
    for (int mi = 0; mi < 4; ++mi)
      af[mi] = *(const short8v*)&As[(wr*64 + mi*16 + r)*32 + g*8];
    #pragma unroll
    for (int ni = 0; ni < 4; ++ni)
      bf_[ni] = *(const short8v*)&Bs[(wc*64 + ni*16 + r)*32 + g*8];
    #pragma unroll
    for (int mi = 0; mi < 4; ++mi)
      #pragma unroll
      for (int ni = 0; ni < 4; ++ni)
        acc[mi][ni] = __builtin_amdgcn_mfma_f32_16x16x32_bf16(af[mi], bf_[ni], acc[mi][ni], 0, 0, 0);
    __syncthreads();                       // LDS reads done before next stage
  }

  const int mbase = m0 + wr*64;
  const int nbase = n0 + wc*64;
  #pragma unroll
  for (int ni = 0; ni < 4; ++ni) {
    const int col = nbase + ni*16 + r;
    const float bv = BIAS ? bias[col] : 0.f;
    #pragma unroll
    for (int mi = 0; mi < 4; ++mi) {
      #pragma unroll
      for (int b4 = 0; b4 < 4; ++b4) {
        const int row = mbase + mi*16 + g*4 + b4;
        float v = acc[mi][ni][b4] + bv;
        if (ADDC) v += Cin[(size_t)row * N + col];
        if (RELU) v = fmaxf(v, 0.f);
        if (OBF16) ((bf16*)Dout)[(size_t)row * N + col] = f2bf(v);
        else       ((float*)Dout)[(size_t)row * N + col] = v;
      }
    }
  }
}

// ---------------------------------------------------------------- weights: W(K,N) f32 -> WT(N,K) bf16 (batched over z)
__global__ __launch_bounds__(256)
void transpose_w(const float* __restrict__ W, bf16* __restrict__ WT, int K, int N,
                 size_t sW, size_t sWT)
{
  const float* Wp = W + (size_t)blockIdx.z * sW;
  bf16* WTp = WT + (size_t)blockIdx.z * sWT;
  __shared__ float tl[32][33];
  const int n0 = blockIdx.x * 32, k0 = blockIdx.y * 32;
  const int r = threadIdx.x >> 5, c = threadIdx.x & 31;
  #pragma unroll
  for (int rr = r; rr < 32; rr += 8) tl[rr][c] = Wp[(size_t)(k0 + rr) * N + n0 + c];
  __syncthreads();
  #pragma unroll
  for (int rr = r; rr < 32; rr += 8) WTp[(size_t)(n0 + rr) * K + k0 + c] = f2bf(tl[c][rr]);
}

// ---------------------------------------------------------------- gather (chunked): X rows [row0, row0+grid)
__global__ __launch_bounds__(256)
void gather_kernel(const int* __restrict__ off_ids, const int* __restrict__ def_ids,
                   const int* __restrict__ off_pos, const int* __restrict__ def_pos,
                   const float* __restrict__ pemb, const float* __restrict__ remb,
                   int row0, bf16* __restrict__ X, int* __restrict__ cbuf)
{
  const int grow = row0 + blockIdx.x;
  const int b = grow / 10, t = grow % 10;
  int pid, pos, role;
  if (t < 5) { pid = off_ids[b*5 + t];   pos = off_pos[b*5 + t];   role = 0; }
  else       { pid = def_ids[b*5 + t-5]; pos = def_pos[b*5 + t-5]; role = 1; }
  const int col = threadIdx.x * 4;       // 0..1020
  const float* src = (col < 512) ? (pemb + (size_t)pid * 512 + col)
                                 : (remb + (size_t)role * 512 + (col - 512));
  f32x4 v = *(const f32x4*)src;
  U4 u;
  u.h[0] = f2bf(v[0]); u.h[1] = f2bf(v[1]); u.h[2] = f2bf(v[2]); u.h[3] = f2bf(v[3]);
  *(short4v*)(X + (size_t)blockIdx.x * 1024 + col) = u.v;
  if (threadIdx.x == 0) cbuf[grow] = role * 5 + pos;
}

// ---------------------------------------------------------------- LayerNorm rows of 512, f32 in -> bf16 out
__global__ __launch_bounds__(256)
void ln_kernel(const float* __restrict__ Zin, const float* __restrict__ gam,
               const float* __restrict__ bet, bf16* __restrict__ outp)
{
  const int w = threadIdx.x >> 6, lane = threadIdx.x & 63;
  const size_t row = (size_t)blockIdx.x * 4 + w;
  const float* zp = Zin + row * 512 + lane * 8;
  f32x4 v0 = *(const f32x4*)zp;
  f32x4 v1 = *(const f32x4*)(zp + 4);
  float s = 0.f, ss = 0.f;
  #pragma unroll
  for (int j = 0; j < 4; ++j) { s += v0[j]; ss += v0[j]*v0[j]; }
  #pragma unroll
  for (int j = 0; j < 4; ++j) { s += v1[j]; ss += v1[j]*v1[j]; }
  for (int d0 = 1; d0 < 64; d0 <<= 1) { s += __shfl_xor(s, d0); ss += __shfl_xor(ss, d0); }
  const float mu = s * (1.f/512.f);
  const float rstd = rsqrtf(ss * (1.f/512.f) - mu*mu + 1e-5f);
  const float* gp = gam + lane * 8;
  const float* bp = bet + lane * 8;
  f32x4 g0 = *(const f32x4*)gp, g1 = *(const f32x4*)(gp + 4);
  f32x4 b0 = *(const f32x4*)bp, b1 = *(const f32x4*)(bp + 4);
  U8 u;
  #pragma unroll
  for (int j = 0; j < 4; ++j) u.h[j]     = f2bf((v0[j]-mu)*rstd*g0[j] + b0[j]);
  #pragma unroll
  for (int j = 0; j < 4; ++j) u.h[4 + j] = f2bf((v1[j]-mu)*rstd*g1[j] + b1[j]);
  *(short8v*)(outp + row * 512 + lane * 8) = u.v;
}

// ---------------------------------------------------------------- attention: one wave per (local b, h)
__global__ __launch_bounds__(256)
void attn_kernel(const bf16* __restrict__ qkv, const int* __restrict__ cbuf,
                 const float* __restrict__ biasL, bf16* __restrict__ O)
{
  __shared__ __align__(16) bf16 Plds[4][256];    // 16x16 per wave
  __shared__ __align__(16) bf16 Vt[4][1024];     // 64x16 per wave (v^T, cols j>=10 zero)
  const int w = threadIdx.x >> 6, lane = threadIdx.x & 63;
  const int wv = blockIdx.x * 4 + w;
  const int b = wv >> 3, h = wv & 7;
  const int r = lane & 15, g = lane >> 4;
  const bf16* base = qkv + (size_t)b * 15360;    // 10*1536
  const bool rv = r < 10;
  const short8v z8 = {0,0,0,0,0,0,0,0};

  short8v aq0 = z8, aq1 = z8, bk0 = z8, bk1 = z8;
  if (rv) {
    const bf16* qp = base + (size_t)r * 1536 + h * 64 + g * 8;
    aq0 = *(const short8v*)qp;
    aq1 = *(const short8v*)(qp + 32);
    bk0 = *(const short8v*)(qp + 512);
    bk1 = *(const short8v*)(qp + 544);
  }
  f32x4 s = {0.f, 0.f, 0.f, 0.f};
  s = __builtin_amdgcn_mfma_f32_16x16x32_bf16(aq0, bk0, s, 0, 0, 0);
  s = __builtin_amdgcn_mfma_f32_16x16x32_bf16(aq1, bk1, s, 0, 0, 0);

  // stage V^T (j cols 10..15 zeroed)
  bf16* V = Vt[w];
  {
    const int j1 = lane >> 3, d0 = (lane & 7) * 8;
    U8 uv; uv.v = *(const short8v*)(base + (size_t)j1 * 1536 + 1024 + h * 64 + d0);
    #pragma unroll
    for (int m2 = 0; m2 < 8; ++m2) V[(d0 + m2) * 16 + j1] = uv.h[m2];
    const int j2 = 8 + j1;
    U8 uv2; uv2.v = z8;
    if (j2 < 10) uv2.v = *(const short8v*)(base + (size_t)j2 * 1536 + 1024 + h * 64 + d0);
    #pragma unroll
    for (int m2 = 0; m2 < 8; ++m2) V[(d0 + m2) * 16 + j2] = uv2.h[m2];
  }

  const int cj = rv ? cbuf[b * 10 + r] : 0;
  float sv[4];
  #pragma unroll
  for (int q4 = 0; q4 < 4; ++q4) {
    const int i = g * 4 + q4;
    float val = s[q4] * 0.125f;                       // 1/sqrt(64)
    if (rv && i < 10) val += biasL[h * 100 + cbuf[b * 10 + i] * 10 + cj];
    if (!rv) val = -1e30f;
    sv[q4] = val;
  }
  float mx[4];
  #pragma unroll
  for (int q4 = 0; q4 < 4; ++q4) mx[q4] = sv[q4];
  for (int d0 = 1; d0 < 16; d0 <<= 1) {
    #pragma unroll
    for (int q4 = 0; q4 < 4; ++q4) mx[q4] = fmaxf(mx[q4], __shfl_xor(mx[q4], d0));
  }
  float pe[4], sm[4];
  #pragma unroll
  for (int q4 = 0; q4 < 4; ++q4) { pe[q4] = __expf(sv[q4] - mx[q4]); sm[q4] = pe[q4]; }
  for (int d0 = 1; d0 < 16; d0 <<= 1) {
    #pragma unroll
    for (int q4 = 0; q4 < 4; ++q4) sm[q4] += __shfl_xor(sm[q4], d0);
  }

  bf16* P = Plds[w];
  #pragma unroll
  for (int q4 = 0; q4 < 4; ++q4) P[(g * 4 + q4) * 16 + r] = f2bf(pe[q4] / sm[q4]);

  short8v pa = z8;
  if (g < 2) pa = *(const short8v*)&P[r * 16 + g * 8];
  #pragma unroll
  for (int db = 0; db < 4; ++db) {
    short8v bv = z8;
    if (g < 2) bv = *(const short8v*)&V[(db * 16 + r) * 16 + g * 8];
    f32x4 o = {0.f, 0.f, 0.f, 0.f};
    o = __builtin_amdgcn_mfma_f32_16x16x32_bf16(pa, bv, o, 0, 0, 0);
    #pragma unroll
    for (int q4 = 0; q4 < 4; ++q4) {
      const int i = g * 4 + q4;
      if (i < 10) O[(size_t)(b * 10 + i) * 512 + h * 64 + db * 16 + r] = f2bf(o[q4]);
    }
  }
}

// ---------------------------------------------------------------- token mean: (8192,10,512) f32 -> (8192,512) bf16
__global__ __launch_bounds__(256)
void mean_kernel(const float* __restrict__ Zin, bf16* __restrict__ zm)
{
  const int idx = blockIdx.x * 256 + threadIdx.x;   // 8192*128
  const int b = idx >> 7, d4 = (idx & 127) << 2;
  const float* p = Zin + (size_t)b * 5120 + d4;
  f32x4 a = {0.f, 0.f, 0.f, 0.f};
  #pragma unroll
  for (int i = 0; i < 10; ++i) a += *(const f32x4*)(p + (size_t)i * 512);
  a *= 0.1f;
  U4 u;
  #pragma unroll
  for (int j = 0; j < 4; ++j) u.h[j] = f2bf(a[j]);
  *(short4v*)(zm + (size_t)b * 512 + d4) = u.v;
}

// ---------------------------------------------------------------- head2: (8192,512)bf16 @ (512,5)f32 + b2
__global__ __launch_bounds__(256)
void head2_kernel(const bf16* __restrict__ hh, const float* __restrict__ W2,
                  const float* __restrict__ b2, float* __restrict__ out)
{
  const int w = threadIdx.x >> 6, lane = threadIdx.x & 63;
  const int b = blockIdx.x * 4 + w;
  U8 u; u.v = *(const short8v*)(hh + (size_t)b * 512 + lane * 8);
  float p[5] = {0.f, 0.f, 0.f, 0.f, 0.f};
  #pragma unroll
  for (int j = 0; j < 8; ++j) {
    const float hf = bf2f(u.h[j]);
    const float* wp = W2 + (size_t)(lane * 8 + j) * 5;
    #pragma unroll
    for (int c = 0; c < 5; ++c) p[c] += hf * wp[c];
  }
  for (int d0 = 1; d0 < 64; d0 <<= 1) {
    #pragma unroll
    for (int c = 0; c < 5; ++c) p[c] += __shfl_xor(p[c], d0);
  }
  if (lane == 0) {
    float* op = out + (size_t)b * 5;
    #pragma unroll
    for (int c = 0; c < 5; ++c) op[c] = p[c] + b2[c];
  }
}

// ----------------------------------------------------------------
extern "C" void kernel_launch(void* const* d_in, const int* in_sizes, int n_in,
                              void* d_out, int out_size, void* d_ws, size_t ws_size,
                              hipStream_t stream)
{
  const int*   off_ids = (const int*)d_in[0];
  const int*   def_ids = (const int*)d_in[1];
  const int*   off_pos = (const int*)d_in[2];
  const int*   def_pos = (const int*)d_in[3];
  const float* pemb    = (const float*)d_in[4];
  const float* remb    = (const float*)d_in[5];
  const float* proj_W1 = (const float*)d_in[6];
  const float* proj_b1 = (const float*)d_in[7];
  const float* proj_W2 = (const float*)d_in[8];
  const float* proj_b2 = (const float*)d_in[9];
  const float* ln1_g   = (const float*)d_in[10];
  const float* ln1_b   = (const float*)d_in[11];
  const float* Wq      = (const float*)d_in[12];
  const float* Wk      = (const float*)d_in[13];
  const float* Wv      = (const float*)d_in[14];
  const float* Wo      = (const float*)d_in[15];
  const float* bias_B  = (const float*)d_in[16];
  const float* ln2_g   = (const float*)d_in[17];
  const float* ln2_b   = (const float*)d_in[18];
  const float* ffn_W1  = (const float*)d_in[19];
  const float* ffn_b1  = (const float*)d_in[20];
  const float* ffn_W2  = (const float*)d_in[21];
  const float* ffn_b2  = (const float*)d_in[22];
  const float* head_W1 = (const float*)d_in[23];
  const float* head_b1 = (const float*)d_in[24];
  const float* head_W2 = (const float*)d_in[25];
  const float* head_b2 = (const float*)d_in[26];
  (void)in_sizes; (void)n_in; (void)out_size;

  char* ws = (char*)d_ws;
  size_t off = 0;
  auto take = [&](size_t bytes) -> char* {
    char* p = ws + off; off += (bytes + 255) & ~(size_t)255; return p;
  };

  // ---- fixed allocations first
  float* Z     = (float*)take(81920ull * 512 * 4);       // residual, f32 (160MiB)
  bf16*  Wp1T  = (bf16*)take(1024ull * 1024 * 2);
  bf16*  Wp2T  = (bf16*)take(512ull * 1024 * 2);
  bf16*  Wh1T  = (bf16*)take(512ull * 512 * 2);
  bf16*  WqkvT = (bf16*)take(4ull * 1536 * 512 * 2);
  bf16*  WoT   = (bf16*)take(4ull * 512 * 512 * 2);
  bf16*  Wf1T  = (bf16*)take(4ull * 2048 * 512 * 2);
  bf16*  Wf2T  = (bf16*)take(4ull * 512 * 2048 * 2);
  int*   cbuf  = (int*)take(81920ull * 4);
  bf16*  zmean = (bf16*)take(8192ull * 512 * 2);
  bf16*  hh    = (bf16*)take(8192ull * 512 * 2);

  // ---- adaptive M-chunk: arena = Mc * 5KB must fit in remaining ws
  const size_t fixed_end = off;
  int Mc = 81920;
  while (Mc > 2560 && fixed_end + (size_t)Mc * 5120 + (1u << 20) > ws_size) Mc >>= 1;
  const int NCH = 81920 / Mc;
  char* arena = ws + fixed_end;

  // ---- weight transpose+convert (f32 (K,N) -> bf16 (N,K)), batched over layers
  auto T = [&](const float* W, bf16* WT, int K, int N, size_t sW, size_t sWT, int nz) {
    transpose_w<<<dim3(N / 32, K / 32, nz), 256, 0, stream>>>(W, WT, K, N, sW, sWT);
  };
  T(proj_W1, Wp1T, 1024, 1024, 0, 0, 1);
  T(proj_W2, Wp2T, 1024, 512, 0, 0, 1);
  T(head_W1, Wh1T, 512, 512, 0, 0, 1);
  T(Wq, WqkvT,          512, 512, 262144, 786432, 4);
  T(Wk, WqkvT + 262144, 512, 512, 262144, 786432, 4);
  T(Wv, WqkvT + 524288, 512, 512, 262144, 786432, 4);
  T(Wo, WoT,            512, 512, 262144, 262144, 4);
  T(ffn_W1, Wf1T, 512, 2048, 1048576, 1048576, 4);
  T(ffn_W2, Wf2T, 2048, 512, 1048576, 1048576, 4);

  // ---- embed gather + proj MLP (chunked)
  for (int c = 0; c < NCH; ++c) {
    const int r0 = c * Mc;
    bf16* Xc  = (bf16*)arena;                          // Mc x 1024 bf16
    bf16* H1c = (bf16*)(arena + (size_t)Mc * 2048);    // Mc x 1024 bf16
    gather_kernel<<<Mc, 256, 0, stream>>>(off_ids, def_ids, off_pos, def_pos,
                                          pemb, remb, r0, Xc, cbuf);
    gemm_bt<true,  true,  false, true ><<<dim3(8, Mc/128),  256, 0, stream>>>(Xc,  Wp1T, proj_b1, nullptr, H1c, Mc, 1024, 1024);
    gemm_bt<false, true,  false, false><<<dim3(4, Mc/128),  256, 0, stream>>>(H1c, Wp2T, proj_b2, nullptr, Z + (size_t)r0 * 512, Mc, 512, 1024);
  }

  // ---- transformer layers (chunked)
  for (int l = 0; l < 4; ++l) {
    for (int c = 0; c < NCH; ++c) {                    // attention sub-block
      const int r0 = c * Mc;
      float* Zc = Z + (size_t)r0 * 512;
      bf16* Z1c  = (bf16*)arena;                       // Mc x 512
      bf16* QKVc = (bf16*)(arena + (size_t)Mc * 1024); // Mc x 1536
      bf16* Oc   = (bf16*)(arena + (size_t)Mc * 4096); // Mc x 512
      ln_kernel<<<Mc/4, 256, 0, stream>>>(Zc, ln1_g + l*512, ln1_b + l*512, Z1c);
      gemm_bt<false, false, false, true ><<<dim3(12, Mc/128), 256, 0, stream>>>(Z1c, WqkvT + (size_t)l * 786432, nullptr, nullptr, QKVc, Mc, 1536, 512);
      attn_kernel<<<Mc/5, 256, 0, stream>>>(QKVc, cbuf + r0, bias_B + (size_t)l * 800, Oc);
      gemm_bt<false, false, true,  false><<<dim3(4, Mc/128),  256, 0, stream>>>(Oc, WoT + (size_t)l * 262144, nullptr, Zc, Zc, Mc, 512, 512);
    }
    for (int c = 0; c < NCH; ++c) {                    // FFN sub-block
      const int r0 = c * Mc;
      float* Zc = Z + (size_t)r0 * 512;
      bf16* Z2c = (bf16*)arena;                        // Mc x 512
      bf16* Hc  = (bf16*)(arena + (size_t)Mc * 1024);  // Mc x 2048
      ln_kernel<<<Mc/4, 256, 0, stream>>>(Zc, ln2_g + l*512, ln2_b + l*512, Z2c);
      gemm_bt<true,  true,  false, true ><<<dim3(16, Mc/128), 256, 0, stream>>>(Z2c, Wf1T + (size_t)l * 1048576, ffn_b1 + (size_t)l * 2048, nullptr, Hc, Mc, 2048, 512);
      gemm_bt<false, true,  true,  false><<<dim3(4, Mc/128),  256, 0, stream>>>(Hc, Wf2T + (size_t)l * 1048576, ffn_b2 + (size_t)l * 512, Zc, Zc, Mc, 512, 2048);
    }
  }

  // ---- head
  mean_kernel<<<4096, 256, 0, stream>>>(Z, zmean);
  gemm_bt<true, true, false, true><<<dim3(4, 64), 256, 0, stream>>>(zmean, Wh1T, head_b1, nullptr, hh, 8192, 512, 512);
  head2_kernel<<<2048, 256, 0, stream>>>(hh, head_W2, head_b2, (float*)d_out);
}